// Round 20
// baseline (184.243 us; speedup 1.0000x reference)
//
#include <hip/hip_runtime.h>
#include <stdint.h>

#define GLOBAL_AS __attribute__((address_space(1)))
#define LDS_AS    __attribute__((address_space(3)))

typedef unsigned short u16;
typedef __attribute__((ext_vector_type(8))) __bf16 bf16x8;
typedef __attribute__((ext_vector_type(4))) float   f32x4;
typedef __attribute__((ext_vector_type(16))) float  f32x16;
typedef __attribute__((ext_vector_type(2))) float   f32x2;
typedef __attribute__((ext_vector_type(4))) u16     u16x4;

#if __has_builtin(__builtin_amdgcn_exp2f)
#define EXP2(x) __builtin_amdgcn_exp2f(x)
#else
#define EXP2(x) __exp2f(x)
#endif

static __device__ __forceinline__ float bf2f(u16 u) {
    union { uint32_t i; float f; } c; c.i = ((uint32_t)u) << 16; return c.f;
}
static __device__ __forceinline__ u16 f2bf(float f) {
    union { float f; uint32_t i; } c; c.f = f;
    uint32_t r = c.i + 0x7fffu + ((c.i >> 16) & 1u);
    return (u16)(r >> 16);
}
static __device__ __forceinline__ u16 f2bf_fast(float f) {   // round-half-up (P values only)
    union { float f; uint32_t i; } c; c.f = f;
    return (u16)((c.i + 0x8000u) >> 16);
}
static __device__ __forceinline__ void gl_lds16(const void* g, void* l) {
    __builtin_amdgcn_global_load_lds((GLOBAL_AS const uint32_t*)g,
                                     (LDS_AS uint32_t*)l, 16, 0, 0);
}
static __device__ __forceinline__ f32x4 mfma16(bf16x8 a, bf16x8 b, f32x4 c) {
    return __builtin_amdgcn_mfma_f32_16x16x32_bf16(a, b, c, 0, 0, 0);
}
static __device__ __forceinline__ f32x16 mfma32(bf16x8 a, bf16x8 b, f32x16 c) {
    return __builtin_amdgcn_mfma_f32_32x32x16_bf16(a, b, c, 0, 0, 0);
}

// ---------------------------------------------------------------- cast fp32->bf16 (8 elems/thread)
__global__ __launch_bounds__(256) void cast5(
    const float* __restrict__ s0, const float* __restrict__ s1,
    const float* __restrict__ s2, const float* __restrict__ s3,
    const float* __restrict__ s4,
    u16* __restrict__ d0, u16* __restrict__ d1, u16* __restrict__ d2,
    u16* __restrict__ d3, u16* __restrict__ d4)
{
    const float* s; u16* d;
    switch (blockIdx.y) {
        case 0: s = s0; d = d0; break;
        case 1: s = s1; d = d1; break;
        case 2: s = s2; d = d2; break;
        case 3: s = s3; d = d3; break;
        default: s = s4; d = d4; break;
    }
    int i = (blockIdx.x * 256 + threadIdx.x) * 8;
    f32x4 v0 = *(const f32x4*)&s[i];
    f32x4 v1 = *(const f32x4*)&s[i + 4];
    u16x4 u0 = { f2bf(v0[0]), f2bf(v0[1]), f2bf(v0[2]), f2bf(v0[3]) };
    u16x4 u1 = { f2bf(v1[0]), f2bf(v1[1]), f2bf(v1[2]), f2bf(v1[3]) };
    *(u16x4*)&d[i] = u0;
    *(u16x4*)&d[i + 4] = u1;
}

// ---------------------------------------------------------------- QKV GEMM, 256x192 tiles, 256 blocks
__global__ __launch_bounds__(512, 2) void gemm_qkv7(
    const u16* __restrict__ x,
    const u16* __restrict__ wq, const u16* __restrict__ wk, const u16* __restrict__ wv,
    const float* __restrict__ bq, const float* __restrict__ bk, const float* __restrict__ bv,
    u16* __restrict__ q, u16* __restrict__ k, u16* __restrict__ vt)
{
    __shared__ u16 SL[4][16384];   // 4 slots x 32KB (slab = BK32: A[256][32] + B[192][32])
    const int tid = threadIdx.x, l = tid & 63, w = tid >> 6;
    const int wm = w >> 2, wn = w & 3;          // 2M x 4N waves; per-wave 128x48
    const int lr = l & 15, lg = l >> 4;
    const int lg2 = lg ^ ((lr >> 1) & 3);       // swizzled k-unit
    const int bid = blockIdx.x;
    const int j = bid >> 3;
    const int bn = (bid & 7) * 4 + (j & 3);     // XCD-local weight panels
    const int bm = j >> 2;

    const u16* Ab = x + (size_t)(bm * 256) * 2048;

    const int uA0 = tid,       rA0 = uA0 >> 2, cA0 = (uA0 & 3) ^ ((rA0 >> 1) & 3);
    const int uA1 = 512 + tid, rA1 = uA1 >> 2, cA1 = (uA1 & 3) ^ ((rA1 >> 1) & 3);
    const u16* apA0 = Ab + (size_t)rA0 * 2048 + cA0 * 8;
    const u16* apA1 = Ab + (size_t)rA1 * 2048 + cA1 * 8;
    const int ub0 = tid;
    int ub1 = 512 + tid; if (ub1 > 767) ub1 = 767;
    const int rB0 = ub0 >> 2, cB0 = (ub0 & 3) ^ ((rB0 >> 1) & 3);
    const int rB1 = ub1 >> 2, cB1 = (ub1 & 3) ^ ((rB1 >> 1) & 3);
    const int gr0 = bn * 192 + rB0, gr1 = bn * 192 + rB1;
    const u16* base0 = gr0 < 2048 ? wq : (gr0 < 4096 ? wk : wv);
    const u16* base1 = gr1 < 2048 ? wq : (gr1 < 4096 ? wk : wv);
    const u16* bpB0 = base0 + (size_t)(gr0 & 2047) * 2048 + cB0 * 8;
    const u16* bpB1 = base1 + (size_t)(gr1 & 2047) * 2048 + cB1 * 8;
    const int dA0 = uA0 * 8, dA1 = uA1 * 8;
    const int dB0 = (1024 + tid) * 8, dB1 = (1536 + tid) * 8;

    auto stageA = [&](u16* slot) {
        gl_lds16(apA0, slot + dA0);
        gl_lds16(apA1, slot + dA1);
        apA0 += 32; apA1 += 32;
    };
    auto stageB = [&](u16* slot) {
        gl_lds16(bpB0, slot + dB0);
        gl_lds16(bpB1, slot + dB1);
        bpB0 += 32; bpB1 += 32;
    };

    f32x4 acc[8][3];
#pragma unroll
    for (int mi = 0; mi < 8; ++mi)
#pragma unroll
        for (int nj = 0; nj < 3; ++nj) acc[mi][nj] = (f32x4){0.f, 0.f, 0.f, 0.f};

    stageA((u16*)SL[0]); stageB((u16*)SL[0]);
    stageA((u16*)SL[1]); stageB((u16*)SL[1]);
    stageA((u16*)SL[2]); stageB((u16*)SL[2]);

    const int ar = wm * 128 + lr;
    const int br = wn * 48 + lr;

    auto iter_body = [&](const u16* As0, const u16* As1, u16* sl3, u16* sl4) {
        const u16* Bs0 = As0 + 8192;
        const u16* Bs1 = As1 + 8192;

        asm volatile("s_waitcnt vmcnt(4)" ::: "memory");
        __builtin_amdgcn_s_barrier();
        __builtin_amdgcn_sched_barrier(0);

        bf16x8 b0[3], alo0[4], ahi0[4], b1[3], alo1[4], ahi1[4];

        // region 1: stage A(next0) | read b0+A-lo s0 (+A-hi s0 behind) | M1
        stageA(sl3);
#pragma unroll
        for (int nj = 0; nj < 3; ++nj)
            b0[nj] = *(const bf16x8*)&Bs0[(br + nj * 16) * 32 + lg2 * 8];
#pragma unroll
        for (int mi = 0; mi < 4; ++mi)
            alo0[mi] = *(const bf16x8*)&As0[(ar + mi * 16) * 32 + lg2 * 8];
#pragma unroll
        for (int mi = 0; mi < 4; ++mi)
            ahi0[mi] = *(const bf16x8*)&As0[(ar + (4 + mi) * 16) * 32 + lg2 * 8];
        __builtin_amdgcn_s_setprio(1);
#pragma unroll
        for (int mi = 0; mi < 4; ++mi)
#pragma unroll
            for (int nj = 0; nj < 3; ++nj)
                acc[mi][nj] = mfma16(alo0[mi], b0[nj], acc[mi][nj]);
        __builtin_amdgcn_s_setprio(0);

        // region 2: stage B(next0) | read b1 + A-lo s1 | M2
        stageB(sl3);
#pragma unroll
        for (int nj = 0; nj < 3; ++nj)
            b1[nj] = *(const bf16x8*)&Bs1[(br + nj * 16) * 32 + lg2 * 8];
#pragma unroll
        for (int mi = 0; mi < 4; ++mi)
            alo1[mi] = *(const bf16x8*)&As1[(ar + mi * 16) * 32 + lg2 * 8];
        __builtin_amdgcn_s_setprio(1);
#pragma unroll
        for (int mi = 0; mi < 4; ++mi)
#pragma unroll
            for (int nj = 0; nj < 3; ++nj)
                acc[4 + mi][nj] = mfma16(ahi0[mi], b0[nj], acc[4 + mi][nj]);
        __builtin_amdgcn_s_setprio(0);

        __builtin_amdgcn_sched_barrier(0);
        __builtin_amdgcn_s_barrier();
        __builtin_amdgcn_sched_barrier(0);

        // region 3: stage A(next1) | read A-hi s1 | M3
        stageA(sl4);
#pragma unroll
        for (int mi = 0; mi < 4; ++mi)
            ahi1[mi] = *(const bf16x8*)&As1[(ar + (4 + mi) * 16) * 32 + lg2 * 8];
        __builtin_amdgcn_s_setprio(1);
#pragma unroll
        for (int mi = 0; mi < 4; ++mi)
#pragma unroll
            for (int nj = 0; nj < 3; ++nj)
                acc[mi][nj] = mfma16(alo1[mi], b1[nj], acc[mi][nj]);
        __builtin_amdgcn_s_setprio(0);

        // region 4: stage B(next1) | M4
        stageB(sl4);
        __builtin_amdgcn_s_setprio(1);
#pragma unroll
        for (int mi = 0; mi < 4; ++mi)
#pragma unroll
            for (int nj = 0; nj < 3; ++nj)
                acc[4 + mi][nj] = mfma16(ahi1[mi], b1[nj], acc[4 + mi][nj]);
        __builtin_amdgcn_s_setprio(0);
    };

#pragma unroll 1
    for (int it2 = 0; it2 < 16; ++it2) {
        iter_body((const u16*)SL[0], (const u16*)SL[1], (u16*)SL[3], (u16*)SL[0]);
        iter_body((const u16*)SL[2], (const u16*)SL[3], (u16*)SL[1], (u16*)SL[2]);
    }
    asm volatile("s_waitcnt vmcnt(0)" ::: "memory");

#pragma unroll
    for (int mi = 0; mi < 8; ++mi) {
        int row0 = bm * 256 + wm * 128 + mi * 16 + lg * 4;   // s index, mult of 4
#pragma unroll
        for (int nj = 0; nj < 3; ++nj) {
            int col = bn * 192 + wn * 48 + nj * 16 + lr;
            int cs = (col >> 11), cc = col & 2047;
            const float* bp = cs == 0 ? bq : (cs == 1 ? bk : bv);
            float bs = bp[cc];
            if (cs == 2) {
                u16x4 pk = { f2bf(acc[mi][nj][0] + bs), f2bf(acc[mi][nj][1] + bs),
                             f2bf(acc[mi][nj][2] + bs), f2bf(acc[mi][nj][3] + bs) };
                *(u16x4*)&vt[(size_t)cc * 2048 + row0] = pk;
            } else {
                u16* C = cs == 0 ? q : k;
#pragma unroll
                for (int reg = 0; reg < 4; ++reg)
                    C[(size_t)(row0 + reg) * 2048 + cc] = f2bf(acc[mi][nj][reg] + bs);
            }
        }
    }
}

// ---------------------------------------------------------------- output GEMM, 128x128 tiles, 256 blocks
__global__ __launch_bounds__(512, 2) void gemm_out5(
    const u16* __restrict__ a, const u16* __restrict__ wo,
    const float* __restrict__ bo, float* __restrict__ out)
{
    __shared__ u16 SL[4][8192];   // 4 slots x 16KB (A[128][32] + B[128][32])
    const int tid = threadIdx.x, l = tid & 63, w = tid >> 6;
    const int wm = w >> 2, wn = w & 3;          // per-wave 64x32
    const int lr = l & 15, lg = l >> 4;
    const int lg2 = lg ^ ((lr >> 1) & 3);
    const int bid = blockIdx.x;
    const int xcd = bid & 7, j = bid >> 3;
    const int bm = xcd * 2 + (j & 1), bn = j >> 1;

    const u16* Ab = a  + (size_t)(bm * 128) * 2048;
    const u16* Bb = wo + (size_t)(bn * 128) * 2048;

    const int r0 = tid >> 2, c0 = (tid & 3) ^ ((r0 >> 1) & 3);
    const u16* apA = Ab + (size_t)r0 * 2048 + c0 * 8;
    const u16* bpB = Bb + (size_t)r0 * 2048 + c0 * 8;
    const int dA = tid * 8, dB = (512 + tid) * 8;

    auto stage = [&](u16* slot) {
        gl_lds16(apA, slot + dA);
        gl_lds16(bpB, slot + dB);
        apA += 32; bpB += 32;
    };

    f32x4 acc[4][2];
#pragma unroll
    for (int mi = 0; mi < 4; ++mi)
#pragma unroll
        for (int nj = 0; nj < 2; ++nj) acc[mi][nj] = (f32x4){0.f, 0.f, 0.f, 0.f};

    stage((u16*)SL[0]); stage((u16*)SL[1]); stage((u16*)SL[2]);   // 6 outstanding

    auto ob = [&](const u16* As, u16* sln) {
        const u16* Bs = As + 4096;
        asm volatile("s_waitcnt vmcnt(4)" ::: "memory");
        __builtin_amdgcn_s_barrier();
        __builtin_amdgcn_sched_barrier(0);

        stage(sln);

        bf16x8 bf[2], af0[2];
#pragma unroll
        for (int nj = 0; nj < 2; ++nj)
            bf[nj] = *(const bf16x8*)&Bs[(wn * 32 + nj * 16 + lr) * 32 + lg2 * 8];
#pragma unroll
        for (int mi = 0; mi < 2; ++mi)
            af0[mi] = *(const bf16x8*)&As[(wm * 64 + mi * 16 + lr) * 32 + lg2 * 8];
        __builtin_amdgcn_s_setprio(1);
#pragma unroll
        for (int mi = 0; mi < 2; ++mi)
#pragma unroll
            for (int nj = 0; nj < 2; ++nj)
                acc[mi][nj] = mfma16(af0[mi], bf[nj], acc[mi][nj]);
        __builtin_amdgcn_s_setprio(0);
        __builtin_amdgcn_s_barrier();
        __builtin_amdgcn_sched_barrier(0);

        bf16x8 af1[2];
#pragma unroll
        for (int mi = 0; mi < 2; ++mi)
            af1[mi] = *(const bf16x8*)&As[(wm * 64 + (2 + mi) * 16 + lr) * 32 + lg2 * 8];
        __builtin_amdgcn_s_setprio(1);
#pragma unroll
        for (int mi = 0; mi < 2; ++mi)
#pragma unroll
            for (int nj = 0; nj < 2; ++nj)
                acc[2 + mi][nj] = mfma16(af1[mi], bf[nj], acc[2 + mi][nj]);
        __builtin_amdgcn_s_setprio(0);
    };

#pragma unroll 1
    for (int it4 = 0; it4 < 16; ++it4) {
        ob((const u16*)SL[0], (u16*)SL[3]);
        ob((const u16*)SL[1], (u16*)SL[0]);
        ob((const u16*)SL[2], (u16*)SL[1]);
        ob((const u16*)SL[3], (u16*)SL[2]);
    }
    asm volatile("s_waitcnt vmcnt(0)" ::: "memory");

#pragma unroll
    for (int mi = 0; mi < 4; ++mi) {
        int row0 = bm * 128 + wm * 64 + mi * 16 + lg * 4;
#pragma unroll
        for (int nj = 0; nj < 2; ++nj) {
            int col = bn * 128 + wn * 32 + nj * 16 + lr;
            float bs = bo[col];
#pragma unroll
            for (int reg = 0; reg < 4; ++reg)
                out[(size_t)(row0 + reg) * 2048 + col] = acc[mi][nj][reg] + bs;
        }
    }
}

// ---------------------------------------------------------------- RMSNorm + RoPE (Q,K only)
__global__ __launch_bounds__(256) void norm_rope(
    const u16* __restrict__ qb, const u16* __restrict__ kb,
    const float* __restrict__ rope, const float* __restrict__ qw, const float* __restrict__ kw,
    u16* __restrict__ qh, u16* __restrict__ kh)
{
    const int tid = threadIdx.x, l = tid & 63, w = tid >> 6;
    const int rowid = blockIdx.x * 4 + w;
    const int h = rowid & 15, s = rowid >> 4;
    const size_t gbase = (size_t)s * 2048 + h * 128 + 2 * l;

    uint32_t qu = *(const uint32_t*)&qb[gbase];
    uint32_t ku = *(const uint32_t*)&kb[gbase];
    float q0 = bf2f((u16)qu), q1 = bf2f((u16)(qu >> 16));
    float k0 = bf2f((u16)ku), k1 = bf2f((u16)(ku >> 16));

    float sq = q0 * q0 + q1 * q1;
    float sk = k0 * k0 + k1 * k1;
#pragma unroll
    for (int m = 1; m < 64; m <<= 1) {
        sq += __shfl_xor(sq, m);
        sk += __shfl_xor(sk, m);
    }
    const float EPS = 1.1920928955078125e-07f;
    const float SCALE = 0.08838834764831845f * 1.4426950408889634f;  // 1/sqrt(128) * log2(e)
    float rq = rsqrtf(sq * (1.f / 128.f) + EPS) * SCALE;
    float rk = rsqrtf(sk * (1.f / 128.f) + EPS);

    f32x2 wq2 = *(const f32x2*)&qw[2 * l];
    f32x2 wk2 = *(const f32x2*)&kw[2 * l];
    float qn0 = q0 * rq * wq2[0], qn1 = q1 * rq * wq2[1];
    float kn0 = k0 * rk * wk2[0], kn1 = k1 * rk * wk2[1];

    f32x4 rr = *(const f32x4*)&rope[(size_t)s * 256 + l * 4];
    float qo0 = rr[0] * qn0 + rr[1] * qn1;
    float qo1 = rr[2] * qn0 + rr[3] * qn1;
    float ko0 = rr[0] * kn0 + rr[1] * kn1;
    float ko1 = rr[2] * kn0 + rr[3] * kn1;

    const size_t obase = ((size_t)h * 2048 + s) * 128 + 2 * l;
    *(uint32_t*)&qh[obase] = (uint32_t)f2bf(qo0) | ((uint32_t)f2bf(qo1) << 16);
    *(uint32_t*)&kh[obase] = (uint32_t)f2bf(ko0) | ((uint32_t)f2bf(ko1) << 16);
}

// ---------------------------------------------------------------- flash attention (fused combine)
// Block = 64 q-rows x full kv: waves {0,1} process kv[0,1024) for q-sub {0,1};
// waves {2,3} process kv[1024,2048) for the same q-rows. Single-buffered
// two-tile LDS (64KB). Epilogue: waves 2,3 dump O-partials+sums to LDS;
// waves 0,1 add, normalize, write final bf16 -> no combine kernel, no Opb.
__global__ __launch_bounds__(256, 2) void attn(
    const u16* __restrict__ qh, const u16* __restrict__ kh,
    const u16* __restrict__ vt, u16* __restrict__ ab)
{
    __shared__ u16 SB[4][16384];   // buf p: K at SB[2p] (64x128), V at SB[2p+1] (128x64)
    const int tid = threadIdx.x, l = tid & 63, w = tid >> 6;
    const int h = blockIdx.y;
    const int p = w >> 1;                       // kv-half
    const int q0 = blockIdx.x * 64 + (w & 1) * 32;
    const int lo = l & 31, hi = l >> 5;
    const float SHIFT = -17.312340490667562f;   // -12 * log2(e)

    const u16* Kh = kh + (size_t)h * 2048 * 128;
    const u16* Vh = vt + (size_t)h * 128 * 2048;
    const int kvbase = p * 1024;
    u16* Ks = (u16*)SB[2 * p];
    u16* Vs = (u16*)SB[2 * p + 1];

    // Q as B-frags: rows q0+lo, k = i*16 + hi*8
    bf16x8 qf[8];
#pragma unroll
    for (int i = 0; i < 8; ++i)
        qf[i] = *(const bf16x8*)&qh[((size_t)h * 2048 + q0 + lo) * 128 + i * 16 + hi * 8];

    f32x16 o[4];
#pragma unroll
    for (int dj = 0; dj < 4; ++dj)
#pragma unroll
        for (int r = 0; r < 16; ++r) o[dj][r] = 0.f;
    float lsum = 0.f;

#pragma unroll 1
    for (int t = 0; t < 16; ++t) {
        const int kv0 = kvbase + t * 64;
        __syncthreads();                 // prev compute done before overwrite
        if ((w & 1) == 0) {
            // waves 0,2: stage K tile of own half (64 rows x 16 units)
#pragma unroll
            for (int i = 0; i < 16; ++i) {
                int u = i * 64 + l;
                int row = u >> 4, cu = (u & 15) ^ (row & 7);
                gl_lds16(Kh + (size_t)(kv0 + row) * 128 + cu * 8, Ks + u * 8);
            }
        } else {
            // waves 1,3: stage V tile of own half (128 rows x 8 units)
#pragma unroll
            for (int i = 0; i < 16; ++i) {
                int u = i * 64 + l;
                int row = u >> 3, cu = (u & 7) ^ (row & 7);
                gl_lds16(Vh + (size_t)row * 2048 + kv0 + cu * 8, Vs + u * 8);
            }
        }
        __syncthreads();                 // drains vmcnt: all tiles staged

        // S^T = K Q^T + SHIFT: chunk c covers kv = 32c..32c+31 of this tile
        f32x16 sc0, sc1;
#pragma unroll
        for (int r = 0; r < 16; ++r) { sc0[r] = SHIFT; sc1[r] = SHIFT; }
        __builtin_amdgcn_s_setprio(1);
#pragma unroll
        for (int i = 0; i < 8; ++i) {
            int u = ((i * 2 + hi) ^ (lo & 7)) * 8;
            bf16x8 kA0 = *(const bf16x8*)&Ks[lo * 128 + u];
            bf16x8 kA1 = *(const bf16x8*)&Ks[(32 + lo) * 128 + u];
            sc0 = mfma32(kA0, qf[i], sc0);
            sc1 = mfma32(kA1, qf[i], sc1);
        }
        __builtin_amdgcn_s_setprio(0);

        // P = exp2(S^T); assemble PV A-frags in regs via pack + shfl_xor(32)
        uint32_t pa[4][4];
        float ls = 0.f;
#pragma unroll
        for (int c = 0; c < 2; ++c) {
            float pv[16];
#pragma unroll
            for (int r = 0; r < 16; ++r) {
                pv[r] = EXP2(c == 0 ? sc0[r] : sc1[r]);
                ls += pv[r];
            }
#pragma unroll
            for (int s = 0; s < 2; ++s) {
                uint32_t pk0a = (uint32_t)f2bf_fast(pv[(2 * s) * 4 + 0]) |
                                ((uint32_t)f2bf_fast(pv[(2 * s) * 4 + 1]) << 16);
                uint32_t pk0b = (uint32_t)f2bf_fast(pv[(2 * s) * 4 + 2]) |
                                ((uint32_t)f2bf_fast(pv[(2 * s) * 4 + 3]) << 16);
                uint32_t pk1a = (uint32_t)f2bf_fast(pv[(2 * s + 1) * 4 + 0]) |
                                ((uint32_t)f2bf_fast(pv[(2 * s + 1) * 4 + 1]) << 16);
                uint32_t pk1b = (uint32_t)f2bf_fast(pv[(2 * s + 1) * 4 + 2]) |
                                ((uint32_t)f2bf_fast(pv[(2 * s + 1) * 4 + 3]) << 16);
                uint32_t x0a = __shfl_xor(pk0a, 32), x0b = __shfl_xor(pk0b, 32);
                uint32_t x1a = __shfl_xor(pk1a, 32), x1b = __shfl_xor(pk1b, 32);
                int ks = c * 2 + s;
                pa[ks][0] = hi ? x1a : pk0a;
                pa[ks][1] = hi ? x1b : pk0b;
                pa[ks][2] = hi ? pk1a : x0a;
                pa[ks][3] = hi ? pk1b : x0b;
            }
        }
        lsum += ls;

        // O += P V
        __builtin_amdgcn_s_setprio(1);
#pragma unroll
        for (int dj = 0; dj < 4; ++dj) {
            int row = dj * 32 + lo;
#pragma unroll
            for (int ks = 0; ks < 4; ++ks) {
                int u = ((ks * 2 + hi) ^ (lo & 7)) * 8;
                bf16x8 vB = *(const bf16x8*)&Vs[row * 64 + u];
                union { uint32_t d[4]; bf16x8 v; } cv;
                cv.d[0] = pa[ks][0]; cv.d[1] = pa[ks][1];
                cv.d[2] = pa[ks][2]; cv.d[3] = pa[ks][3];
                o[dj] = mfma32(cv.v, vB, o[dj]);
            }
        }
        __builtin_amdgcn_s_setprio(0);
    }

    lsum += __shfl_xor(lsum, 32);   // both hi halves now hold denom(q = q0+lo) of own kv-half

    // ---- in-block combine: waves 2,3 publish partials; waves 0,1 finish.
    __syncthreads();                 // last compute done; staging LDS now dead
    float* sf = (float*)&SB[0][0];   // scratch: 2 regions x 4096 f32 + 64 sums
    if (w >= 2) {
#pragma unroll
        for (int dj = 0; dj < 4; ++dj)
#pragma unroll
            for (int r = 0; r < 16; ++r) {
                int qq = (r & 3) + 8 * (r >> 2) + 4 * hi;
                sf[(w - 2) * 4096 + qq * 128 + dj * 32 + lo] = o[dj][r];
            }
        if (hi == 0)
            sf[8192 + (w - 2) * 32 + lo] = lsum;
    }
    __syncthreads();
    if (w < 2) {
        float lt = lsum + sf[8192 + w * 32 + lo];   // total denom for q = q0+lo
        float rl = 1.0f / lt;
#pragma unroll
        for (int dj = 0; dj < 4; ++dj)
#pragma unroll
            for (int r = 0; r < 16; ++r) {
                int qq = (r & 3) + 8 * (r >> 2) + 4 * hi;
                float part = sf[w * 4096 + qq * 128 + dj * 32 + lo];
                float rlq = __shfl(rl, qq);
                ab[(size_t)(q0 + qq) * 2048 + h * 128 + dj * 32 + lo] =
                    f2bf((o[dj][r] + part) * rlq);
            }
    }
}

// ---------------------------------------------------------------- launch
extern "C" void kernel_launch(void* const* d_in, const int* in_sizes, int n_in,
                              void* d_out, int out_size, void* d_ws, size_t ws_size,
                              hipStream_t stream)
{
    (void)in_sizes; (void)n_in; (void)out_size;
    const float* x    = (const float*)d_in[0];
    const float* rope = (const float*)d_in[1];
    const float* wq   = (const float*)d_in[2];
    const float* bq   = (const float*)d_in[3];
    const float* wk   = (const float*)d_in[4];
    const float* bk   = (const float*)d_in[5];
    const float* wv   = (const float*)d_in[6];
    const float* bv   = (const float*)d_in[7];
    const float* qw   = (const float*)d_in[8];
    const float* kw   = (const float*)d_in[9];
    const float* wo   = (const float*)d_in[10];
    const float* bo   = (const float*)d_in[11];
    float* out = (float*)d_out;

    const size_t NE = 2048ull * 2048ull;
    if (ws_size < 13 * NE * 2) return;
    u16* p = (u16*)d_ws;
    u16* xb  = p; p += NE;
    u16* wqb = p; p += NE;
    u16* wkb = p; p += NE;
    u16* wvb = p; p += NE;
    u16* wob = p; p += NE;
    u16* qb  = p; p += NE;
    u16* kb  = p; p += NE;
    u16* vb  = p; p += NE;   // unused (layout stability)
    u16* qhb = p; p += NE;
    u16* khb = p; p += NE;
    u16* ab  = p; p += NE;   // NOT last: gemm_out5's A-staging overruns <=4.3KB into vtb
    u16* vtb = p; p += NE;
    u16* spare = p; p += NE; // keeps all staged-buffer overruns inside the allocation
    (void)spare; (void)vb;

    cast5<<<dim3(2048, 5), 256, 0, stream>>>(x, wq, wk, wv, wo, xb, wqb, wkb, wvb, wob);
    gemm_qkv7<<<256, 512, 0, stream>>>(xb, wqb, wkb, wvb, bq, bk, bv, qb, kb, vtb);
    norm_rope<<<8192, 256, 0, stream>>>(qb, kb, rope, qw, kw, qhb, khb);
    attn<<<dim3(32, 16), 256, 0, stream>>>(qhb, khb, vtb, ab);
    gemm_out5<<<256, 512, 0, stream>>>(ab, wob, bo, out);
}

// Round 21
// 154.246 us; speedup vs baseline: 1.1945x; 1.1945x over previous
//
#include <hip/hip_runtime.h>
#include <stdint.h>

#define GLOBAL_AS __attribute__((address_space(1)))
#define LDS_AS    __attribute__((address_space(3)))

typedef unsigned short u16;
typedef __attribute__((ext_vector_type(8))) __bf16 bf16x8;
typedef __attribute__((ext_vector_type(4))) float   f32x4;
typedef __attribute__((ext_vector_type(2))) float   f32x2;
typedef __attribute__((ext_vector_type(4))) u16     u16x4;

#if __has_builtin(__builtin_amdgcn_exp2f)
#define EXP2(x) __builtin_amdgcn_exp2f(x)
#else
#define EXP2(x) __exp2f(x)
#endif

static __device__ __forceinline__ float bf2f(u16 u) {
    union { uint32_t i; float f; } c; c.i = ((uint32_t)u) << 16; return c.f;
}
static __device__ __forceinline__ u16 f2bf(float f) {
    union { float f; uint32_t i; } c; c.f = f;
    uint32_t r = c.i + 0x7fffu + ((c.i >> 16) & 1u);
    return (u16)(r >> 16);
}
static __device__ __forceinline__ u16 f2bf_fast(float f) {   // round-half-up (P values only)
    union { float f; uint32_t i; } c; c.f = f;
    return (u16)((c.i + 0x8000u) >> 16);
}
static __device__ __forceinline__ void gl_lds16(const void* g, void* l) {
    __builtin_amdgcn_global_load_lds((GLOBAL_AS const uint32_t*)g,
                                     (LDS_AS uint32_t*)l, 16, 0, 0);
}
static __device__ __forceinline__ f32x4 mfma16(bf16x8 a, bf16x8 b, f32x4 c) {
    return __builtin_amdgcn_mfma_f32_16x16x32_bf16(a, b, c, 0, 0, 0);
}

// ---------------------------------------------------------------- cast fp32->bf16 (8 elems/thread)
__global__ __launch_bounds__(256) void cast5(
    const float* __restrict__ s0, const float* __restrict__ s1,
    const float* __restrict__ s2, const float* __restrict__ s3,
    const float* __restrict__ s4,
    u16* __restrict__ d0, u16* __restrict__ d1, u16* __restrict__ d2,
    u16* __restrict__ d3, u16* __restrict__ d4)
{
    const float* s; u16* d;
    switch (blockIdx.y) {
        case 0: s = s0; d = d0; break;
        case 1: s = s1; d = d1; break;
        case 2: s = s2; d = d2; break;
        case 3: s = s3; d = d3; break;
        default: s = s4; d = d4; break;
    }
    int i = (blockIdx.x * 256 + threadIdx.x) * 8;
    f32x4 v0 = *(const f32x4*)&s[i];
    f32x4 v1 = *(const f32x4*)&s[i + 4];
    u16x4 u0 = { f2bf(v0[0]), f2bf(v0[1]), f2bf(v0[2]), f2bf(v0[3]) };
    u16x4 u1 = { f2bf(v1[0]), f2bf(v1[1]), f2bf(v1[2]), f2bf(v1[3]) };
    *(u16x4*)&d[i] = u0;
    *(u16x4*)&d[i + 4] = u1;
}

// ---------------------------------------------------------------- QKV GEMM, 256x192 tiles, 256 blocks
// XCD affinity: each XCD owns 4 weight panels (3MB, L2-resident), streams A.
// V columns written transposed into vt (no separate transpose kernel).
__global__ __launch_bounds__(512, 2) void gemm_qkv7(
    const u16* __restrict__ x,
    const u16* __restrict__ wq, const u16* __restrict__ wk, const u16* __restrict__ wv,
    const float* __restrict__ bq, const float* __restrict__ bk, const float* __restrict__ bv,
    u16* __restrict__ q, u16* __restrict__ k, u16* __restrict__ vt)
{
    __shared__ u16 SL[4][16384];   // 4 slots x 32KB (slab = BK32: A[256][32] + B[192][32])
    const int tid = threadIdx.x, l = tid & 63, w = tid >> 6;
    const int wm = w >> 2, wn = w & 3;          // 2M x 4N waves; per-wave 128x48
    const int lr = l & 15, lg = l >> 4;
    const int lg2 = lg ^ ((lr >> 1) & 3);       // swizzled k-unit
    const int bid = blockIdx.x;
    const int j = bid >> 3;
    const int bn = (bid & 7) * 4 + (j & 3);     // XCD-local weight panels
    const int bm = j >> 2;

    const u16* Ab = x + (size_t)(bm * 256) * 2048;

    const int uA0 = tid,       rA0 = uA0 >> 2, cA0 = (uA0 & 3) ^ ((rA0 >> 1) & 3);
    const int uA1 = 512 + tid, rA1 = uA1 >> 2, cA1 = (uA1 & 3) ^ ((rA1 >> 1) & 3);
    const u16* apA0 = Ab + (size_t)rA0 * 2048 + cA0 * 8;
    const u16* apA1 = Ab + (size_t)rA1 * 2048 + cA1 * 8;
    const int ub0 = tid;
    int ub1 = 512 + tid; if (ub1 > 767) ub1 = 767;
    const int rB0 = ub0 >> 2, cB0 = (ub0 & 3) ^ ((rB0 >> 1) & 3);
    const int rB1 = ub1 >> 2, cB1 = (ub1 & 3) ^ ((rB1 >> 1) & 3);
    const int gr0 = bn * 192 + rB0, gr1 = bn * 192 + rB1;
    const u16* base0 = gr0 < 2048 ? wq : (gr0 < 4096 ? wk : wv);
    const u16* base1 = gr1 < 2048 ? wq : (gr1 < 4096 ? wk : wv);
    const u16* bpB0 = base0 + (size_t)(gr0 & 2047) * 2048 + cB0 * 8;
    const u16* bpB1 = base1 + (size_t)(gr1 & 2047) * 2048 + cB1 * 8;
    const int dA0 = uA0 * 8, dA1 = uA1 * 8;
    const int dB0 = (1024 + tid) * 8, dB1 = (1536 + tid) * 8;

    auto stageA = [&](u16* slot) {
        gl_lds16(apA0, slot + dA0);
        gl_lds16(apA1, slot + dA1);
        apA0 += 32; apA1 += 32;
    };
    auto stageB = [&](u16* slot) {
        gl_lds16(bpB0, slot + dB0);
        gl_lds16(bpB1, slot + dB1);
        bpB0 += 32; bpB1 += 32;
    };

    f32x4 acc[8][3];
#pragma unroll
    for (int mi = 0; mi < 8; ++mi)
#pragma unroll
        for (int nj = 0; nj < 3; ++nj) acc[mi][nj] = (f32x4){0.f, 0.f, 0.f, 0.f};

    stageA((u16*)SL[0]); stageB((u16*)SL[0]);
    stageA((u16*)SL[1]); stageB((u16*)SL[1]);
    stageA((u16*)SL[2]); stageB((u16*)SL[2]);

    const int ar = wm * 128 + lr;
    const int br = wn * 48 + lr;

    auto iter_body = [&](const u16* As0, const u16* As1, u16* sl3, u16* sl4) {
        const u16* Bs0 = As0 + 8192;
        const u16* Bs1 = As1 + 8192;

        asm volatile("s_waitcnt vmcnt(4)" ::: "memory");
        __builtin_amdgcn_s_barrier();
        __builtin_amdgcn_sched_barrier(0);

        bf16x8 b0[3], alo0[4], ahi0[4], b1[3], alo1[4], ahi1[4];

        // region 1: stage A(next0) | read b0+A-lo s0 (+A-hi s0 behind) | M1
        stageA(sl3);
#pragma unroll
        for (int nj = 0; nj < 3; ++nj)
            b0[nj] = *(const bf16x8*)&Bs0[(br + nj * 16) * 32 + lg2 * 8];
#pragma unroll
        for (int mi = 0; mi < 4; ++mi)
            alo0[mi] = *(const bf16x8*)&As0[(ar + mi * 16) * 32 + lg2 * 8];
#pragma unroll
        for (int mi = 0; mi < 4; ++mi)
            ahi0[mi] = *(const bf16x8*)&As0[(ar + (4 + mi) * 16) * 32 + lg2 * 8];
        __builtin_amdgcn_s_setprio(1);
#pragma unroll
        for (int mi = 0; mi < 4; ++mi)
#pragma unroll
            for (int nj = 0; nj < 3; ++nj)
                acc[mi][nj] = mfma16(alo0[mi], b0[nj], acc[mi][nj]);
        __builtin_amdgcn_s_setprio(0);

        // region 2: stage B(next0) | read b1 + A-lo s1 | M2
        stageB(sl3);
#pragma unroll
        for (int nj = 0; nj < 3; ++nj)
            b1[nj] = *(const bf16x8*)&Bs1[(br + nj * 16) * 32 + lg2 * 8];
#pragma unroll
        for (int mi = 0; mi < 4; ++mi)
            alo1[mi] = *(const bf16x8*)&As1[(ar + mi * 16) * 32 + lg2 * 8];
        __builtin_amdgcn_s_setprio(1);
#pragma unroll
        for (int mi = 0; mi < 4; ++mi)
#pragma unroll
            for (int nj = 0; nj < 3; ++nj)
                acc[4 + mi][nj] = mfma16(ahi0[mi], b0[nj], acc[4 + mi][nj]);
        __builtin_amdgcn_s_setprio(0);

        // mid barrier: M2's operand wait retired ALL s0 reads -> sl4 restage safe
        __builtin_amdgcn_sched_barrier(0);
        __builtin_amdgcn_s_barrier();
        __builtin_amdgcn_sched_barrier(0);

        // region 3: stage A(next1) | read A-hi s1 | M3
        stageA(sl4);
#pragma unroll
        for (int mi = 0; mi < 4; ++mi)
            ahi1[mi] = *(const bf16x8*)&As1[(ar + (4 + mi) * 16) * 32 + lg2 * 8];
        __builtin_amdgcn_s_setprio(1);
#pragma unroll
        for (int mi = 0; mi < 4; ++mi)
#pragma unroll
            for (int nj = 0; nj < 3; ++nj)
                acc[mi][nj] = mfma16(alo1[mi], b1[nj], acc[mi][nj]);
        __builtin_amdgcn_s_setprio(0);

        // region 4: stage B(next1) | M4
        stageB(sl4);
        __builtin_amdgcn_s_setprio(1);
#pragma unroll
        for (int mi = 0; mi < 4; ++mi)
#pragma unroll
            for (int nj = 0; nj < 3; ++nj)
                acc[4 + mi][nj] = mfma16(ahi1[mi], b1[nj], acc[4 + mi][nj]);
        __builtin_amdgcn_s_setprio(0);
    };

#pragma unroll 1
    for (int it2 = 0; it2 < 16; ++it2) {
        iter_body((const u16*)SL[0], (const u16*)SL[1], (u16*)SL[3], (u16*)SL[0]);
        iter_body((const u16*)SL[2], (const u16*)SL[3], (u16*)SL[1], (u16*)SL[2]);
    }
    asm volatile("s_waitcnt vmcnt(0)" ::: "memory");

#pragma unroll
    for (int mi = 0; mi < 8; ++mi) {
        int row0 = bm * 256 + wm * 128 + mi * 16 + lg * 4;   // s index, mult of 4
#pragma unroll
        for (int nj = 0; nj < 3; ++nj) {
            int col = bn * 192 + wn * 48 + nj * 16 + lr;
            int cs = (col >> 11), cc = col & 2047;
            const float* bp = cs == 0 ? bq : (cs == 1 ? bk : bv);
            float bs = bp[cc];
            if (cs == 2) {
                // V: store transposed, 4 regs = 4 consecutive s -> one 8B store
                u16x4 pk = { f2bf(acc[mi][nj][0] + bs), f2bf(acc[mi][nj][1] + bs),
                             f2bf(acc[mi][nj][2] + bs), f2bf(acc[mi][nj][3] + bs) };
                *(u16x4*)&vt[(size_t)cc * 2048 + row0] = pk;
            } else {
                u16* C = cs == 0 ? q : k;
#pragma unroll
                for (int reg = 0; reg < 4; ++reg)
                    C[(size_t)(row0 + reg) * 2048 + cc] = f2bf(acc[mi][nj][reg] + bs);
            }
        }
    }
}

// ---------------------------------------------------------------- output GEMM, 128x128 tiles, 256 blocks
__global__ __launch_bounds__(512, 2) void gemm_out5(
    const u16* __restrict__ a, const u16* __restrict__ wo,
    const float* __restrict__ bo, float* __restrict__ out)
{
    __shared__ u16 SL[4][8192];   // 4 slots x 16KB (A[128][32] + B[128][32])
    const int tid = threadIdx.x, l = tid & 63, w = tid >> 6;
    const int wm = w >> 2, wn = w & 3;          // per-wave 64x32
    const int lr = l & 15, lg = l >> 4;
    const int lg2 = lg ^ ((lr >> 1) & 3);
    const int bid = blockIdx.x;
    const int xcd = bid & 7, j = bid >> 3;
    const int bm = xcd * 2 + (j & 1), bn = j >> 1;

    const u16* Ab = a  + (size_t)(bm * 128) * 2048;
    const u16* Bb = wo + (size_t)(bn * 128) * 2048;

    const int r0 = tid >> 2, c0 = (tid & 3) ^ ((r0 >> 1) & 3);
    const u16* apA = Ab + (size_t)r0 * 2048 + c0 * 8;
    const u16* bpB = Bb + (size_t)r0 * 2048 + c0 * 8;
    const int dA = tid * 8, dB = (512 + tid) * 8;

    auto stage = [&](u16* slot) {
        gl_lds16(apA, slot + dA);
        gl_lds16(bpB, slot + dB);
        apA += 32; bpB += 32;
    };

    f32x4 acc[4][2];
#pragma unroll
    for (int mi = 0; mi < 4; ++mi)
#pragma unroll
        for (int nj = 0; nj < 2; ++nj) acc[mi][nj] = (f32x4){0.f, 0.f, 0.f, 0.f};

    stage((u16*)SL[0]); stage((u16*)SL[1]); stage((u16*)SL[2]);   // 6 outstanding

    auto ob = [&](const u16* As, u16* sln) {
        const u16* Bs = As + 4096;
        asm volatile("s_waitcnt vmcnt(4)" ::: "memory");
        __builtin_amdgcn_s_barrier();
        __builtin_amdgcn_sched_barrier(0);

        stage(sln);

        bf16x8 bf[2], af0[2];
#pragma unroll
        for (int nj = 0; nj < 2; ++nj)
            bf[nj] = *(const bf16x8*)&Bs[(wn * 32 + nj * 16 + lr) * 32 + lg2 * 8];
#pragma unroll
        for (int mi = 0; mi < 2; ++mi)
            af0[mi] = *(const bf16x8*)&As[(wm * 64 + mi * 16 + lr) * 32 + lg2 * 8];
        __builtin_amdgcn_s_setprio(1);
#pragma unroll
        for (int mi = 0; mi < 2; ++mi)
#pragma unroll
            for (int nj = 0; nj < 2; ++nj)
                acc[mi][nj] = mfma16(af0[mi], bf[nj], acc[mi][nj]);
        __builtin_amdgcn_s_setprio(0);
        __builtin_amdgcn_s_barrier();
        __builtin_amdgcn_sched_barrier(0);

        bf16x8 af1[2];
#pragma unroll
        for (int mi = 0; mi < 2; ++mi)
            af1[mi] = *(const bf16x8*)&As[(wm * 64 + (2 + mi) * 16 + lr) * 32 + lg2 * 8];
        __builtin_amdgcn_s_setprio(1);
#pragma unroll
        for (int mi = 0; mi < 2; ++mi)
#pragma unroll
            for (int nj = 0; nj < 2; ++nj)
                acc[2 + mi][nj] = mfma16(af1[mi], bf[nj], acc[2 + mi][nj]);
        __builtin_amdgcn_s_setprio(0);
    };

#pragma unroll 1
    for (int it4 = 0; it4 < 16; ++it4) {
        ob((const u16*)SL[0], (u16*)SL[3]);
        ob((const u16*)SL[1], (u16*)SL[0]);
        ob((const u16*)SL[2], (u16*)SL[1]);
        ob((const u16*)SL[3], (u16*)SL[2]);
    }
    asm volatile("s_waitcnt vmcnt(0)" ::: "memory");

#pragma unroll
    for (int mi = 0; mi < 4; ++mi) {
        int row0 = bm * 128 + wm * 64 + mi * 16 + lg * 4;
#pragma unroll
        for (int nj = 0; nj < 2; ++nj) {
            int col = bn * 128 + wn * 32 + nj * 16 + lr;
            float bs = bo[col];
#pragma unroll
            for (int reg = 0; reg < 4; ++reg)
                out[(size_t)(row0 + reg) * 2048 + col] = acc[mi][nj][reg] + bs;
        }
    }
}

// ---------------------------------------------------------------- RMSNorm + RoPE (Q,K only)
__global__ __launch_bounds__(256) void norm_rope(
    const u16* __restrict__ qb, const u16* __restrict__ kb,
    const float* __restrict__ rope, const float* __restrict__ qw, const float* __restrict__ kw,
    u16* __restrict__ qh, u16* __restrict__ kh)
{
    const int tid = threadIdx.x, l = tid & 63, w = tid >> 6;
    const int rowid = blockIdx.x * 4 + w;
    const int h = rowid & 15, s = rowid >> 4;
    const size_t gbase = (size_t)s * 2048 + h * 128 + 2 * l;

    uint32_t qu = *(const uint32_t*)&qb[gbase];
    uint32_t ku = *(const uint32_t*)&kb[gbase];
    float q0 = bf2f((u16)qu), q1 = bf2f((u16)(qu >> 16));
    float k0 = bf2f((u16)ku), k1 = bf2f((u16)(ku >> 16));

    float sq = q0 * q0 + q1 * q1;
    float sk = k0 * k0 + k1 * k1;
#pragma unroll
    for (int m = 1; m < 64; m <<= 1) {
        sq += __shfl_xor(sq, m);
        sk += __shfl_xor(sk, m);
    }
    const float EPS = 1.1920928955078125e-07f;
    const float SCALE = 0.08838834764831845f * 1.4426950408889634f;  // 1/sqrt(128) * log2(e)
    float rq = rsqrtf(sq * (1.f / 128.f) + EPS) * SCALE;
    float rk = rsqrtf(sk * (1.f / 128.f) + EPS);

    f32x2 wq2 = *(const f32x2*)&qw[2 * l];
    f32x2 wk2 = *(const f32x2*)&kw[2 * l];
    float qn0 = q0 * rq * wq2[0], qn1 = q1 * rq * wq2[1];
    float kn0 = k0 * rk * wk2[0], kn1 = k1 * rk * wk2[1];

    f32x4 rr = *(const f32x4*)&rope[(size_t)s * 256 + l * 4];
    float qo0 = rr[0] * qn0 + rr[1] * qn1;
    float qo1 = rr[2] * qn0 + rr[3] * qn1;
    float ko0 = rr[0] * kn0 + rr[1] * kn1;
    float ko1 = rr[2] * kn0 + rr[3] * kn1;

    const size_t obase = ((size_t)h * 2048 + s) * 128 + 2 * l;
    *(uint32_t*)&qh[obase] = (uint32_t)f2bf(qo0) | ((uint32_t)f2bf(qo1) << 16);
    *(uint32_t*)&kh[obase] = (uint32_t)f2bf(ko0) | ((uint32_t)f2bf(ko1) << 16);
}

// ---------------------------------------------------------------- flash attention
// 32 q-rows/wave, 128 q-rows/block, kv-split x2, no-max exp2 softmax,
// bf16 unnormalized partials + fp32 row-sum. (Best-measured config, R16.)
__global__ __launch_bounds__(256, 2) void attn(
    const u16* __restrict__ qh, const u16* __restrict__ kh,
    const u16* __restrict__ vt, u16* __restrict__ Opb, float* __restrict__ Lp)
{
    __shared__ u16 Ks[64 * 128];
    __shared__ u16 Vs[128 * 64];
    __shared__ u16 Ps[4][32 * 68];
    const int tid = threadIdx.x, l = tid & 63, w = tid >> 6;
    const int h = blockIdx.z, half = blockIdx.y;
    const int q0 = blockIdx.x * 128 + w * 32;
    const int lr = l & 15, lg = l >> 4;
    const float SHIFT = -17.312340490667562f;   // -12 * log2(e)

    const u16* Kh = kh + (size_t)h * 2048 * 128;
    const u16* Vh = vt + (size_t)h * 128 * 2048;
    const int kvbase = half * 1024;

    bf16x8 qf[2][4];
#pragma unroll
    for (int am = 0; am < 2; ++am)
#pragma unroll
        for (int kk = 0; kk < 4; ++kk)
            qf[am][kk] = *(const bf16x8*)
                &qh[((size_t)h * 2048 + q0 + am * 16 + lr) * 128 + kk * 32 + lg * 8];

    bf16x8 onesf;
#pragma unroll
    for (int jj = 0; jj < 8; ++jj) {
        union { u16 u; __bf16 b; } cb; cb.u = 0x3F80;
        onesf[jj] = cb.b;
    }

    f32x4 o[2][8];
#pragma unroll
    for (int am = 0; am < 2; ++am)
#pragma unroll
        for (int dj = 0; dj < 8; ++dj) o[am][dj] = (f32x4){0.f, 0.f, 0.f, 0.f};
    f32x4 ol[2] = { (f32x4){0.f, 0.f, 0.f, 0.f}, (f32x4){0.f, 0.f, 0.f, 0.f} };

#pragma unroll 1
    for (int t = 0; t < 16; ++t) {
        const int kv0 = kvbase + t * 64;
        __syncthreads();
#pragma unroll
        for (int r = 0; r < 4; ++r) {
            int c = w * 4 + r;
            {
                int row = c * 4 + (l >> 4);
                int u = (l & 15) ^ (row & 7);
                gl_lds16(Kh + (size_t)(kv0 + row) * 128 + u * 8, &Ks[c * 512 + l * 8]);
            }
            {
                int row = c * 8 + (l >> 3);
                int u = (l & 7) ^ (row & 7);
                gl_lds16(Vh + (size_t)row * 2048 + kv0 + u * 8, &Vs[c * 512 + l * 8]);
            }
        }
        __syncthreads();

        f32x4 sc[2][4];
#pragma unroll
        for (int am = 0; am < 2; ++am)
#pragma unroll
            for (int nj = 0; nj < 4; ++nj)
                sc[am][nj] = (f32x4){SHIFT, SHIFT, SHIFT, SHIFT};
        __builtin_amdgcn_s_setprio(1);
#pragma unroll
        for (int kk = 0; kk < 4; ++kk)
#pragma unroll
            for (int nj = 0; nj < 4; ++nj) {
                int n = nj * 16 + lr;
                bf16x8 b = *(const bf16x8*)&Ks[n * 128 + ((kk * 4 + lg) ^ (n & 7)) * 8];
#pragma unroll
                for (int am = 0; am < 2; ++am)
                    sc[am][nj] = mfma16(qf[am][kk], b, sc[am][nj]);
            }
        __builtin_amdgcn_s_setprio(0);

#pragma unroll
        for (int am = 0; am < 2; ++am)
#pragma unroll
            for (int reg = 0; reg < 4; ++reg)
#pragma unroll
                for (int nj = 0; nj < 4; ++nj)
                    Ps[w][(am * 16 + lg * 4 + reg) * 68 + nj * 16 + lr] =
                        f2bf_fast(EXP2(sc[am][nj][reg]));
        asm volatile("s_waitcnt lgkmcnt(0)" ::: "memory");
        __builtin_amdgcn_sched_barrier(0);

        bf16x8 pa[2][2];
#pragma unroll
        for (int am = 0; am < 2; ++am)
#pragma unroll
            for (int kk2 = 0; kk2 < 2; ++kk2) {
                union { u16x4 h4[2]; bf16x8 v8; } cvt;
                cvt.h4[0] = *(const u16x4*)&Ps[w][(am * 16 + lr) * 68 + kk2 * 32 + lg * 8];
                cvt.h4[1] = *(const u16x4*)&Ps[w][(am * 16 + lr) * 68 + kk2 * 32 + lg * 8 + 4];
                pa[am][kk2] = cvt.v8;
            }
        __builtin_amdgcn_s_setprio(1);
#pragma unroll
        for (int am = 0; am < 2; ++am)
#pragma unroll
            for (int kk2 = 0; kk2 < 2; ++kk2)
                ol[am] = mfma16(pa[am][kk2], onesf, ol[am]);
#pragma unroll
        for (int dj = 0; dj < 8; ++dj)
#pragma unroll
            for (int kk2 = 0; kk2 < 2; ++kk2) {
                int n = dj * 16 + lr;
                bf16x8 b = *(const bf16x8*)&Vs[n * 64 + ((kk2 * 4 + lg) ^ (n & 7)) * 8];
#pragma unroll
                for (int am = 0; am < 2; ++am)
                    o[am][dj] = mfma16(pa[am][kk2], b, o[am][dj]);
            }
        __builtin_amdgcn_s_setprio(0);
    }

    if (lr == 0) {
#pragma unroll
        for (int am = 0; am < 2; ++am)
#pragma unroll
            for (int reg = 0; reg < 4; ++reg)
                Lp[(half * 16 + h) * 2048 + q0 + am * 16 + lg * 4 + reg] = ol[am][reg];
    }
#pragma unroll
    for (int am = 0; am < 2; ++am)
#pragma unroll
        for (int dj = 0; dj < 8; ++dj)
#pragma unroll
            for (int reg = 0; reg < 4; ++reg)
                Opb[((size_t)(half * 2048) + q0 + am * 16 + lg * 4 + reg) * 2048 +
                    h * 128 + dj * 16 + lr] = f2bf(o[am][dj][reg]);
}

// ---------------------------------------------------------------- combine kv halves (bf16 partials) -> bf16
__global__ __launch_bounds__(256) void combine(
    const u16* __restrict__ Opb, const float* __restrict__ Lp, u16* __restrict__ ab)
{
    int idx = (blockIdx.x * 256 + threadIdx.x) * 4;
    int s = idx >> 11, c = idx & 2047, h = c >> 7;
    u16x4 a4 = *(const u16x4*)&Opb[(size_t)s * 2048 + c];
    u16x4 b4 = *(const u16x4*)&Opb[(size_t)(2048 + s) * 2048 + c];
    float rl = 1.0f / (Lp[h * 2048 + s] + Lp[(16 + h) * 2048 + s]);
    u16x4 u = { f2bf((bf2f(a4[0]) + bf2f(b4[0])) * rl),
                f2bf((bf2f(a4[1]) + bf2f(b4[1])) * rl),
                f2bf((bf2f(a4[2]) + bf2f(b4[2])) * rl),
                f2bf((bf2f(a4[3]) + bf2f(b4[3])) * rl) };
    *(u16x4*)&ab[idx] = u;
}

// ---------------------------------------------------------------- launch
extern "C" void kernel_launch(void* const* d_in, const int* in_sizes, int n_in,
                              void* d_out, int out_size, void* d_ws, size_t ws_size,
                              hipStream_t stream)
{
    (void)in_sizes; (void)n_in; (void)out_size;
    const float* x    = (const float*)d_in[0];
    const float* rope = (const float*)d_in[1];
    const float* wq   = (const float*)d_in[2];
    const float* bq   = (const float*)d_in[3];
    const float* wk   = (const float*)d_in[4];
    const float* bk   = (const float*)d_in[5];
    const float* wv   = (const float*)d_in[6];
    const float* bv   = (const float*)d_in[7];
    const float* qw   = (const float*)d_in[8];
    const float* kw   = (const float*)d_in[9];
    const float* wo   = (const float*)d_in[10];
    const float* bo   = (const float*)d_in[11];
    float* out = (float*)d_out;

    const size_t NE = 2048ull * 2048ull;
    if (ws_size < 13 * NE * 2) return;
    u16* p = (u16*)d_ws;
    u16* xb  = p; p += NE;
    u16* wqb = p; p += NE;
    u16* wkb = p; p += NE;
    u16* wvb = p; p += NE;
    u16* wob = p; p += NE;
    u16* qb  = p; p += NE;
    u16* kb  = p; p += NE;
    u16* vb  = p; p += NE;   // unused (layout stability)
    u16* qhb = p; p += NE;
    u16* khb = p; p += NE;
    u16* ab  = p; p += NE;   // NOT last: gemm_out5's A-staging overruns <=4.3KB into vtb
    u16* vtb = p; p += NE;
    u16* spare = p; p += NE; // keeps all staged-buffer overruns inside the allocation
    (void)spare; (void)vb;

    u16*   Opb = xb;          // [2][2048][2048] bf16 partial O over xb,wqb (dead after qkv)
    float* Lp  = (float*)qb;  // [2][16][2048] fp32 (dead after norm_rope)

    cast5<<<dim3(2048, 5), 256, 0, stream>>>(x, wq, wk, wv, wo, xb, wqb, wkb, wvb, wob);
    gemm_qkv7<<<256, 512, 0, stream>>>(xb, wqb, wkb, wvb, bq, bk, bv, qb, kb, vtb);
    norm_rope<<<8192, 256, 0, stream>>>(qb, kb, rope, qw, kw, qhb, khb);
    attn<<<dim3(16, 2, 16), 256, 0, stream>>>(qhb, khb, vtb, Opb, Lp);
    combine<<<4096, 256, 0, stream>>>(Opb, Lp, ab);
    gemm_out5<<<256, 512, 0, stream>>>(ab, wob, bo, out);
}